// Round 9
// baseline (100.019 us; speedup 1.0000x reference)
//
#include <hip/hip_runtime.h>
#include <math.h>

// LDDMM variational RHS, Gaussian kernel sigma=0.1, B=1, N=8192, D=3.
// out[0:N*3]     = dmom_i = (1/sig^2) * (x_i * sum_j W_ij - sum_j W_ij x_j)
// out[N*3:2*N*3] = dcp_i  = sum_j K_ij p_j
// K_ij = exp(-|x_i-x_j|^2/(2 sig^2)), W_ij = K_ij*(p_i.p_j), p=clamp(mom,-1,1)
//
// R9: eight rounds of counter-fitting say the pair loop has a ~46cy/m-iter
// issue floor (~33us) invariant to LDS traffic (4x swing), VALU packing
// (2x), and ws traffic (2x); the two-phase structure adds ~6-10us on top
// (reduce dispatch + 16-33MB ws round-trip). Fuse to ONE kernel: R1's
// atomic accumulation into d_out (per-(i,chunk) partials are linear), R6's
// winning shape (2 packed i/thread, JC=64, 1024 blocks = 4 blk/CU), packed
// fp32 VOP3P math, and the identity wsum_i = p_i . dcp_i (drops the per-pair
// wsum accumulate: 14 pk ops + 2 exp per v2f pair-group). d_ws is unused.
// Harness's 256MiB d_ws 0xAA re-poison (~43-48us fill) is a fixed tax.

#define NPTS 8192
#define N3   (NPTS * 3)
#define BI   256
#define IBLK (NPTS / (BI * 2))       // 16 i-blocks (2 packed i's per thread)
#define JC   64                      // j-chunks
#define JLEN (NPTS / JC)             // 128 j's per chunk

// exp(-d2/(2*0.1^2)) = exp2(d2 * (-50*log2(e)))
#define COEF    (-72.134752044448170f)
#define M2COEF  (144.269504088896340f)     // -2*COEF
#define UNSC100 (0.69314718055994531f)     // 100 / M2COEF

typedef float v2f __attribute__((ext_vector_type(2)));

__device__ __forceinline__ v2f vsplat(float s) { v2f r; r.x = s; r.y = s; return r; }

__device__ __forceinline__ v2f pkfma(v2f a, v2f b, v2f c) {
#if __has_builtin(__builtin_elementwise_fma)
    return __builtin_elementwise_fma(a, b, c);
#else
    v2f r; r.x = fmaf(a.x, b.x, c.x); r.y = fmaf(a.y, b.y, c.y); return r;
#endif
}

__device__ __forceinline__ float fast_exp2(float x) {
#if __has_builtin(__builtin_amdgcn_exp2f)
    return __builtin_amdgcn_exp2f(x);
#else
    return exp2f(x);
#endif
}

__device__ __forceinline__ float clamp1(float v) {
    return fminf(fmaxf(v, -1.0f), 1.0f);
}

__global__ __launch_bounds__(BI, 4) void lddmm_fused(const float* __restrict__ mom,
                                                     const float* __restrict__ cp,
                                                     float* __restrict__ out) {
    const int ib = (int)blockIdx.x / JC;
    const int jc = (int)blockIdx.x % JC;
    const int t  = (int)threadIdx.x;
    const int i0 = ib * (BI * 2) + t;     // packed .x
    const int i1 = i0 + BI;               // packed .y

    // i-side data packed {i0, i1}
    v2f xi0, xi1, xi2, ci, pi0, pi1, pi2;
    {
        const float a0 = cp[i0 * 3 + 0], a1 = cp[i0 * 3 + 1], a2 = cp[i0 * 3 + 2];
        const float b0 = cp[i1 * 3 + 0], b1 = cp[i1 * 3 + 1], b2 = cp[i1 * 3 + 2];
        xi0.x = a0; xi0.y = b0;
        xi1.x = a1; xi1.y = b1;
        xi2.x = a2; xi2.y = b2;
        ci.x = COEF * (a0 * a0 + a1 * a1 + a2 * a2);
        ci.y = COEF * (b0 * b0 + b1 * b1 + b2 * b2);
        pi0.x = clamp1(mom[i0 * 3 + 0]); pi0.y = clamp1(mom[i1 * 3 + 0]);
        pi1.x = clamp1(mom[i0 * 3 + 1]); pi1.y = clamp1(mom[i1 * 3 + 1]);
        pi2.x = clamp1(mom[i0 * 3 + 2]); pi2.y = clamp1(mom[i1 * 3 + 2]);
    }

    // Stage j-chunk: shx = {M2COEF*xj, COEF*|xj|^2}, shp = {pj clamped, 0}
    __shared__ float4 shx[JLEN];
    __shared__ float4 shp[JLEN];
    if (t < JLEN) {
        const int j = jc * JLEN + t;
        const float x0 = cp[j * 3 + 0], x1 = cp[j * 3 + 1], x2 = cp[j * 3 + 2];
        shx[t] = make_float4(M2COEF * x0, M2COEF * x1, M2COEF * x2,
                             COEF * (x0 * x0 + x1 * x1 + x2 * x2));
        shp[t] = make_float4(clamp1(mom[j * 3 + 0]), clamp1(mom[j * 3 + 1]),
                             clamp1(mom[j * 3 + 2]), 0.0f);
    }
    __syncthreads();

    v2f dcp0 = vsplat(0.f), dcp1 = vsplat(0.f), dcp2 = vsplat(0.f);
    v2f wx0 = vsplat(0.f), wx1 = vsplat(0.f), wx2 = vsplat(0.f);

#pragma unroll 8
    for (int jj = 0; jj < JLEN; ++jj) {
        const float4 xj = shx[jj];   // wave-uniform -> LDS broadcast
        const float4 pj = shp[jj];
        v2f arg = ci + vsplat(xj.w);             // 1 pk_add + 3 pk_fma
        arg = pkfma(xi2, vsplat(xj.z), arg);
        arg = pkfma(xi1, vsplat(xj.y), arg);
        arg = pkfma(xi0, vsplat(xj.x), arg);
        v2f K;                                   // 2 trans
        K.x = fast_exp2(arg.x);
        K.y = fast_exp2(arg.y);
        v2f pd = pi0 * vsplat(pj.x);             // 1 pk_mul + 2 pk_fma
        pd = pkfma(pi1, vsplat(pj.y), pd);
        pd = pkfma(pi2, vsplat(pj.z), pd);
        const v2f W = K * pd;                    // 1 pk_mul
        dcp0 = pkfma(K, vsplat(pj.x), dcp0);     // 3 pk_fma
        dcp1 = pkfma(K, vsplat(pj.y), dcp1);
        dcp2 = pkfma(K, vsplat(pj.z), dcp2);
        wx0 = pkfma(W, vsplat(xj.x), wx0);       // 3 pk_fma (M2COEF-scaled)
        wx1 = pkfma(W, vsplat(xj.y), wx1);
        wx2 = pkfma(W, vsplat(xj.z), wx2);
        // NOTE: no wsum accumulate -- wsum_chunk = p_i . dcp_chunk (identity)
    }

    // Epilogue: reconstruct chunk wsum, form chunk dmom, accumulate.
    // dmom_c = 100*x_i*wsum_c - (100/M2COEF)*wxs_c
    v2f wsum = pi0 * dcp0;
    wsum = pkfma(pi1, dcp1, wsum);
    wsum = pkfma(pi2, dcp2, wsum);

    atomicAdd(&out[i0 * 3 + 0], fmaf(100.0f * xi0.x, wsum.x, -UNSC100 * wx0.x));
    atomicAdd(&out[i0 * 3 + 1], fmaf(100.0f * xi1.x, wsum.x, -UNSC100 * wx1.x));
    atomicAdd(&out[i0 * 3 + 2], fmaf(100.0f * xi2.x, wsum.x, -UNSC100 * wx2.x));
    atomicAdd(&out[N3 + i0 * 3 + 0], dcp0.x);
    atomicAdd(&out[N3 + i0 * 3 + 1], dcp1.x);
    atomicAdd(&out[N3 + i0 * 3 + 2], dcp2.x);

    atomicAdd(&out[i1 * 3 + 0], fmaf(100.0f * xi0.y, wsum.y, -UNSC100 * wx0.y));
    atomicAdd(&out[i1 * 3 + 1], fmaf(100.0f * xi1.y, wsum.y, -UNSC100 * wx1.y));
    atomicAdd(&out[i1 * 3 + 2], fmaf(100.0f * xi2.y, wsum.y, -UNSC100 * wx2.y));
    atomicAdd(&out[N3 + i1 * 3 + 0], dcp0.y);
    atomicAdd(&out[N3 + i1 * 3 + 1], dcp1.y);
    atomicAdd(&out[N3 + i1 * 3 + 2], dcp2.y);
}

extern "C" void kernel_launch(void* const* d_in, const int* in_sizes, int n_in,
                              void* d_out, int out_size, void* d_ws, size_t ws_size,
                              hipStream_t stream) {
    const float* mom = (const float*)d_in[0];
    const float* cp  = (const float*)d_in[1];
    float* out = (float*)d_out;

    // out is poisoned 0xAA before every launch; atomics need a zero base.
    hipMemsetAsync(out, 0, (size_t)out_size * sizeof(float), stream);
    hipLaunchKernelGGL(lddmm_fused, dim3(IBLK * JC), dim3(BI), 0, stream, mom, cp, out);
}